// Round 3
// baseline (203.520 us; speedup 1.0000x reference)
//
#include <hip/hip_runtime.h>
#include <hip/hip_bf16.h>

// SS3D selective-scan block, MI355X (gfx950)
// B=2, D_INNER=96, D_MODEL=96, D_STATE=16, DT_RANK=6, L=12^3=1728, 8L=13824
//
//  S1: xz = x @ in_proj_w.T  -> xxT[b][c][l] (conv layout), z[b][l][c]
//  S2: depthwise conv3d 3x3x3 SAME + bias + silu -> xconv[b][c][l]
//  S3: 8 direction permutations -> xs[b][d][p]
//  S4: x_dbl = x_proj_w @ xs; delta = softplus(...); Bst/Cst[b][p][n]
//  S5: chunked scan, n=16 states IN REGISTERS per (b,d,chunk)-thread,
//      LDS-staged transposed tiles; A: local (prodA, H); prefix in-place; B: replay+y
//  S6: mean over 8 dirs, LayerNorm, *silu(z), @ out_proj_w.T

#define LSP 1728
#define P8  13824
#define CS  64
#define NC  216

__device__ __forceinline__ float sigmoidf_(float v) { return 1.f / (1.f + __expf(-v)); }

// ---------- S1: input projection ----------
__global__ void s1_inproj(const float* __restrict__ x, const float* __restrict__ w,
                          float* __restrict__ xxT, float* __restrict__ z) {
  __shared__ float xr[96];
  int bl = blockIdx.x;            // b*1728 + l
  int b = bl / LSP, l = bl % LSP;
  int tid = threadIdx.x;          // 0..191 -> output channel c'
  if (tid < 96) xr[tid] = x[bl * 96 + tid];
  __syncthreads();
  float acc = 0.f;
  const float* wr = w + tid * 96;
#pragma unroll 8
  for (int c = 0; c < 96; c++) acc = fmaf(xr[c], wr[c], acc);
  if (tid < 96) xxT[(b * 96 + tid) * LSP + l] = acc;
  else          z[(b * LSP + l) * 96 + (tid - 96)] = acc;
}

// ---------- S2: depthwise conv3d + silu ----------
__global__ void s2_conv(const float* __restrict__ xxT, const float* __restrict__ cw,
                        const float* __restrict__ cb, float* __restrict__ xconv) {
  __shared__ float w[27];
  int bx = blockIdx.x;                 // b*(96*9) + c*9 + lb
  int b = bx / (96 * 9);
  int rem = bx % (96 * 9);
  int c = rem / 9, lb = rem % 9;
  int tid = threadIdx.x;               // 0..191
  if (tid < 27) w[tid] = cw[c * 27 + tid];
  __syncthreads();
  int l = lb * 192 + tid;
  int a = l / 144, r2 = l % 144, bb = r2 / 12, cc = r2 % 12;
  const float* xp = xxT + (b * 96 + c) * LSP;
  float acc = cb[c];
#pragma unroll
  for (int kd = -1; kd <= 1; kd++) {
    int ia = a + kd; if (ia < 0 || ia >= 12) continue;
#pragma unroll
    for (int kw = -1; kw <= 1; kw++) {
      int ib = bb + kw; if (ib < 0 || ib >= 12) continue;
#pragma unroll
      for (int kh = -1; kh <= 1; kh++) {
        int ic = cc + kh; if (ic < 0 || ic >= 12) continue;
        acc = fmaf(xp[ia * 144 + ib * 12 + ic], w[(kd + 1) * 9 + (kw + 1) * 3 + (kh + 1)], acc);
      }
    }
  }
  xconv[(b * 96 + c) * LSP + l] = acc * sigmoidf_(acc);
}

// ---------- S3: direction gather ----------
__global__ void s3_dirs(const float* __restrict__ xconv, float* __restrict__ xs) {
  int t = blockIdx.x * 256 + threadIdx.x;     // < 2*96*13824
  int bd = t / P8, p = t % P8;
  int k = p / LSP, l = p % LSP;
  int lp = (k & 1) ? (LSP - 1 - l) : l;
  int a = lp / 144, r = lp % 144, bb = r / 12, cc = r % 12;
  int s;
  switch (k >> 1) {
    case 0:  s = a * 144 + cc * 12 + bb; break;   // swap(W,H)
    case 1:  s = cc * 144 + bb * 12 + a; break;   // swap(D,H)
    case 2:  s = bb * 144 + a * 12 + cc; break;   // swap(D,W)
    default: s = lp; break;                        // identity
  }
  xs[t] = xconv[bd * LSP + s];
}

// ---------- S4: x_proj + dt projection + softplus (LDS-tiled) ----------
__global__ void s4_proj(const float* __restrict__ xs, const float* __restrict__ xpw,
                        const float* __restrict__ dtw, const float* __restrict__ dtb,
                        float* __restrict__ delta, float* __restrict__ Bst,
                        float* __restrict__ Cst) {
  __shared__ float xt[96][64];     // 24 KB   xs tile
  __shared__ float w[40 * 96];     // 15 KB   x_proj_w padded to 40 rows
  __shared__ float dwv[96 * 6];
  __shared__ float dbv[96];
  __shared__ float accS[6][64];    // dt-rank sums broadcast
  int tid = threadIdx.x;
  int blk = blockIdx.x;
  int b = blk / (P8 / 64);
  int p0 = (blk % (P8 / 64)) * 64;
  for (int i = tid; i < 40 * 96; i += 256) w[i] = (i < 38 * 96) ? xpw[i] : 0.f;
  for (int i = tid; i < 96 * 6; i += 256) dwv[i] = dtw[i];
  if (tid < 96) dbv[tid] = dtb[tid];
  int pl = tid & 63, cg = tid >> 6;   // lane-in-wave = p, wave = channel group
  const float* xsb = xs + (size_t)b * 96 * P8 + p0 + pl;
#pragma unroll
  for (int d0 = 0; d0 < 96; d0 += 4)
    xt[d0 + cg][pl] = xsb[(size_t)(d0 + cg) * P8];
  __syncthreads();

  int c0 = cg * 10;
  float acc[10];
#pragma unroll
  for (int j = 0; j < 10; j++) acc[j] = 0.f;
  for (int d = 0; d < 96; d++) {
    float xv = xt[d][pl];
#pragma unroll
    for (int j = 0; j < 10; j++) acc[j] = fmaf(w[(c0 + j) * 96 + d], xv, acc[j]);
  }
  if (cg == 0) {
#pragma unroll
    for (int j = 0; j < 6; j++) accS[j][pl] = acc[j];
  }
  size_t pi = (size_t)b * P8 + p0 + pl;
#pragma unroll
  for (int j = 0; j < 10; j++) {
    int c = c0 + j;
    if (c >= 6 && c < 22)       Bst[pi * 16 + (c - 6)]  = acc[j];
    else if (c >= 22 && c < 38) Cst[pi * 16 + (c - 22)] = acc[j];
  }
  __syncthreads();
  float a0 = accS[0][pl], a1 = accS[1][pl], a2 = accS[2][pl];
  float a3 = accS[3][pl], a4 = accS[4][pl], a5 = accS[5][pl];
  float* dout = delta + (size_t)b * 96 * P8 + p0 + pl;
#pragma unroll 4
  for (int dd = 0; dd < 24; dd++) {
    int d = cg * 24 + dd;
    const float* dwr = dwv + d * 6;
    float s = dbv[d];
    s = fmaf(dwr[0], a0, s); s = fmaf(dwr[1], a1, s); s = fmaf(dwr[2], a2, s);
    s = fmaf(dwr[3], a3, s); s = fmaf(dwr[4], a4, s); s = fmaf(dwr[5], a5, s);
    float sp = (s > 20.f) ? s : __logf(1.f + __expf(s));
    dout[(size_t)d * P8] = sp;
  }
}

// ---------- S5A: per-chunk scan, n in registers ----------
// grid = 2*NC blocks (b, chunk), 128 threads (d = tid, active d<96)
#define SCAN_STEP_A(bn, n) { \
    float dA = exp2f(dv * Av[n]); \
    Pv[n] *= dA; \
    Hv[n] = fmaf(dA, Hv[n], (bn) * dvx); }

__global__ void s5a_chunk(const float* __restrict__ delta, const float* __restrict__ xs,
                          const float* __restrict__ Bst, const float* __restrict__ A_logs,
                          float* __restrict__ P, float* __restrict__ H) {
  __shared__ float sdT[CS][97];
  __shared__ float sxT[CS][97];
  __shared__ float sB[CS][16];
  int bx = blockIdx.x;
  int b = bx / NC, c = bx % NC;
  int tid = threadIdx.x;
  int p0 = c * CS;
#pragma unroll
  for (int k = 0; k < 12; k++) {
    int idx = tid + 128 * k;            // < 1536
    int d = idx >> 4, i4 = idx & 15;
    float4 dv4 = *(const float4*)(delta + (size_t)(b * 96 + d) * P8 + p0 + i4 * 4);
    float4 xv4 = *(const float4*)(xs    + (size_t)(b * 96 + d) * P8 + p0 + i4 * 4);
    int i = i4 * 4;
    sdT[i][d] = dv4.x; sdT[i+1][d] = dv4.y; sdT[i+2][d] = dv4.z; sdT[i+3][d] = dv4.w;
    sxT[i][d] = xv4.x; sxT[i+1][d] = xv4.y; sxT[i+2][d] = xv4.z; sxT[i+3][d] = xv4.w;
  }
  {
    const float4* gB = (const float4*)(Bst + (size_t)(b * P8 + p0) * 16);
    float4* sB4 = (float4*)&sB[0][0];
    sB4[tid] = gB[tid];
    sB4[tid + 128] = gB[tid + 128];
  }
  __syncthreads();
  int d = tid;
  if (d < 96) {
    float Av[16];
    const float4* Ar = (const float4*)(A_logs + d * 16);
#pragma unroll
    for (int j = 0; j < 4; j++) {
      float4 a4 = Ar[j];
      Av[4*j+0] = -__expf(a4.x) * 1.44269504f;
      Av[4*j+1] = -__expf(a4.y) * 1.44269504f;
      Av[4*j+2] = -__expf(a4.z) * 1.44269504f;
      Av[4*j+3] = -__expf(a4.w) * 1.44269504f;
    }
    float Pv[16], Hv[16];
#pragma unroll
    for (int n = 0; n < 16; n++) { Pv[n] = 1.f; Hv[n] = 0.f; }
#pragma unroll 4
    for (int i = 0; i < CS; i++) {
      float dv = sdT[i][d];
      float xv = sxT[i][d];
      float dvx = dv * xv;
      float4 b0 = *(const float4*)&sB[i][0];
      float4 b1 = *(const float4*)&sB[i][4];
      float4 b2 = *(const float4*)&sB[i][8];
      float4 b3 = *(const float4*)&sB[i][12];
      SCAN_STEP_A(b0.x, 0)  SCAN_STEP_A(b0.y, 1)  SCAN_STEP_A(b0.z, 2)  SCAN_STEP_A(b0.w, 3)
      SCAN_STEP_A(b1.x, 4)  SCAN_STEP_A(b1.y, 5)  SCAN_STEP_A(b1.z, 6)  SCAN_STEP_A(b1.w, 7)
      SCAN_STEP_A(b2.x, 8)  SCAN_STEP_A(b2.y, 9)  SCAN_STEP_A(b2.z, 10) SCAN_STEP_A(b2.w, 11)
      SCAN_STEP_A(b3.x, 12) SCAN_STEP_A(b3.y, 13) SCAN_STEP_A(b3.z, 14) SCAN_STEP_A(b3.w, 15)
    }
    size_t idx = ((size_t)(b * 96 + d) * NC + c) * 16;
    float4* Pp = (float4*)(P + idx);
    float4* Hp = (float4*)(H + idx);
#pragma unroll
    for (int j = 0; j < 4; j++) {
      Pp[j] = make_float4(Pv[4*j], Pv[4*j+1], Pv[4*j+2], Pv[4*j+3]);
      Hp[j] = make_float4(Hv[4*j], Hv[4*j+1], Hv[4*j+2], Hv[4*j+3]);
    }
  }
}

// ---------- S5A2: chunk prefix, Hinit written IN-PLACE into P ----------
__global__ void s5a2_prefix(float* __restrict__ P, const float* __restrict__ H) {
  int t = blockIdx.x * 256 + threadIdx.x;   // < 2*96*16 = 3072
  int bd = t >> 4, n = t & 15;
  float* Pp = P + (size_t)bd * NC * 16 + n;
  const float* Hp = H + (size_t)bd * NC * 16 + n;
  float carry = 0.f;
#pragma unroll 4
  for (int c = 0; c < NC; c++) {
    float pv = Pp[(size_t)c * 16];
    float hv = Hp[(size_t)c * 16];
    Pp[(size_t)c * 16] = carry;          // init state for chunk c
    carry = fmaf(pv, carry, hv);
  }
}

// ---------- S5B: replay with init, emit y ----------
#define SCAN_STEP_B(bn, cn, n) { \
    float dA = exp2f(dv * Av[n]); \
    hv[n] = fmaf(dA, hv[n], (bn) * dvx); \
    y = fmaf(hv[n], (cn), y); }

__global__ void s5b_scan(const float* __restrict__ delta, const float* __restrict__ xs,
                         const float* __restrict__ Bst, const float* __restrict__ Cst,
                         const float* __restrict__ Hinit, const float* __restrict__ A_logs,
                         const float* __restrict__ Ds, float* __restrict__ yT) {
  __shared__ float sdT[CS][97];
  __shared__ float sxT[CS][97];
  __shared__ float sB[CS][16];
  __shared__ float sC[CS][16];
  int bx = blockIdx.x;
  int b = bx / NC, c = bx % NC;
  int tid = threadIdx.x;
  int p0 = c * CS;
#pragma unroll
  for (int k = 0; k < 12; k++) {
    int idx = tid + 128 * k;
    int d = idx >> 4, i4 = idx & 15;
    float4 dv4 = *(const float4*)(delta + (size_t)(b * 96 + d) * P8 + p0 + i4 * 4);
    float4 xv4 = *(const float4*)(xs    + (size_t)(b * 96 + d) * P8 + p0 + i4 * 4);
    int i = i4 * 4;
    sdT[i][d] = dv4.x; sdT[i+1][d] = dv4.y; sdT[i+2][d] = dv4.z; sdT[i+3][d] = dv4.w;
    sxT[i][d] = xv4.x; sxT[i+1][d] = xv4.y; sxT[i+2][d] = xv4.z; sxT[i+3][d] = xv4.w;
  }
  {
    const float4* gB = (const float4*)(Bst + (size_t)(b * P8 + p0) * 16);
    const float4* gC = (const float4*)(Cst + (size_t)(b * P8 + p0) * 16);
    float4* sB4 = (float4*)&sB[0][0];
    float4* sC4 = (float4*)&sC[0][0];
    sB4[tid] = gB[tid];       sB4[tid + 128] = gB[tid + 128];
    sC4[tid] = gC[tid];       sC4[tid + 128] = gC[tid + 128];
  }
  __syncthreads();
  int d = tid;
  if (d < 96) {
    float Av[16];
    const float4* Ar = (const float4*)(A_logs + d * 16);
#pragma unroll
    for (int j = 0; j < 4; j++) {
      float4 a4 = Ar[j];
      Av[4*j+0] = -__expf(a4.x) * 1.44269504f;
      Av[4*j+1] = -__expf(a4.y) * 1.44269504f;
      Av[4*j+2] = -__expf(a4.z) * 1.44269504f;
      Av[4*j+3] = -__expf(a4.w) * 1.44269504f;
    }
    float hv[16];
    size_t idx = ((size_t)(b * 96 + d) * NC + c) * 16;
    const float4* Hi = (const float4*)(Hinit + idx);
#pragma unroll
    for (int j = 0; j < 4; j++) {
      float4 h4 = Hi[j];
      hv[4*j+0] = h4.x; hv[4*j+1] = h4.y; hv[4*j+2] = h4.z; hv[4*j+3] = h4.w;
    }
    float dsv = Ds[d];
    float* yp = yT + (size_t)(b * P8 + p0) * 96 + d;
#pragma unroll 4
    for (int i = 0; i < CS; i++) {
      float dv = sdT[i][d];
      float xv = sxT[i][d];
      float dvx = dv * xv;
      float y = dsv * xv;
      float4 b0 = *(const float4*)&sB[i][0];
      float4 b1 = *(const float4*)&sB[i][4];
      float4 b2 = *(const float4*)&sB[i][8];
      float4 b3 = *(const float4*)&sB[i][12];
      float4 c0 = *(const float4*)&sC[i][0];
      float4 c1 = *(const float4*)&sC[i][4];
      float4 c2 = *(const float4*)&sC[i][8];
      float4 c3 = *(const float4*)&sC[i][12];
      SCAN_STEP_B(b0.x, c0.x, 0)  SCAN_STEP_B(b0.y, c0.y, 1)  SCAN_STEP_B(b0.z, c0.z, 2)  SCAN_STEP_B(b0.w, c0.w, 3)
      SCAN_STEP_B(b1.x, c1.x, 4)  SCAN_STEP_B(b1.y, c1.y, 5)  SCAN_STEP_B(b1.z, c1.z, 6)  SCAN_STEP_B(b1.w, c1.w, 7)
      SCAN_STEP_B(b2.x, c2.x, 8)  SCAN_STEP_B(b2.y, c2.y, 9)  SCAN_STEP_B(b2.z, c2.z, 10) SCAN_STEP_B(b2.w, c2.w, 11)
      SCAN_STEP_B(b3.x, c3.x, 12) SCAN_STEP_B(b3.y, c3.y, 13) SCAN_STEP_B(b3.z, c3.z, 14) SCAN_STEP_B(b3.w, c3.w, 15)
      yp[(size_t)i * 96] = y;
    }
  }
}

// ---------- S6: dir-mean + LayerNorm + gate + out_proj ----------
__global__ void s6_out(const float* __restrict__ yT, const float* __restrict__ z,
                       const float* __restrict__ lnw, const float* __restrict__ lnb,
                       const float* __restrict__ wout, float* __restrict__ out) {
  __shared__ float wl[96 * 97];   // padded stride 97 -> conflict-free
  __shared__ float g[96];
  __shared__ float r1[128], r2[128];
  int tid = threadIdx.x;          // 128
  for (int i = tid; i < 96 * 96; i += 128) {
    int cc = i / 96, dd = i % 96;
    wl[cc * 97 + dd] = wout[i];
  }
  int bx = blockIdx.x;            // b*216 + lb  (8 l's per block)
  int b = bx / 216, lb = bx % 216;
  __syncthreads();
  for (int j = 0; j < 8; j++) {
    int l = lb * 8 + j;
    float ym = 0.f, zv = 0.f;
    if (tid < 96) {
      const float* yp = yT + (size_t)(b * P8 + l) * 96 + tid;
#pragma unroll
      for (int k = 0; k < 8; k++) ym += yp[(size_t)k * LSP * 96];
      ym *= 0.125f;
      zv = z[(b * LSP + l) * 96 + tid];
    }
    r1[tid] = (tid < 96) ? ym : 0.f;
    r2[tid] = (tid < 96) ? ym * ym : 0.f;
    __syncthreads();
    for (int s = 64; s > 0; s >>= 1) {
      if (tid < s) { r1[tid] += r1[tid + s]; r2[tid] += r2[tid + s]; }
      __syncthreads();
    }
    float mu = r1[0] * (1.f / 96.f);
    float var = r2[0] * (1.f / 96.f) - mu * mu;
    float rstd = rsqrtf(var + 1e-5f);
    if (tid < 96) {
      float yn = (ym - mu) * rstd * lnw[tid] + lnb[tid];
      g[tid] = yn * (zv * sigmoidf_(zv));
    }
    __syncthreads();
    if (tid < 96) {
      float acc = 0.f;
#pragma unroll 8
      for (int dd = 0; dd < 96; dd++) acc = fmaf(g[dd], wl[tid * 97 + dd], acc);
      out[(b * LSP + l) * 96 + tid] = acc;
    }
    __syncthreads();
  }
}

extern "C" void kernel_launch(void* const* d_in, const int* in_sizes, int n_in,
                              void* d_out, int out_size, void* d_ws, size_t ws_size,
                              hipStream_t stream) {
  const float* x          = (const float*)d_in[0];
  const float* in_proj_w  = (const float*)d_in[1];
  const float* conv_w     = (const float*)d_in[2];
  const float* conv_b     = (const float*)d_in[3];
  const float* x_proj_w   = (const float*)d_in[4];
  const float* dt_w       = (const float*)d_in[5];
  const float* dt_b       = (const float*)d_in[6];
  const float* A_logs     = (const float*)d_in[7];
  const float* Ds         = (const float*)d_in[8];
  const float* ln_w       = (const float*)d_in[9];
  const float* ln_b       = (const float*)d_in[10];
  const float* out_proj_w = (const float*)d_in[11];
  float* out = (float*)d_out;

  float* ws    = (float*)d_ws;
  float* z     = ws;                 // 331776
  float* xxT   = z + 331776;         // 331776   (dead after s2; P overlays xxT+xconv)
  float* xconv = xxT + 331776;       // 331776   (dead after s3)
  float* xs    = xconv + 331776;     // 2654208
  float* delta = xs + 2654208;       // 2654208
  float* Bst   = delta + 2654208;    // 442368
  float* Cst   = Bst + 442368;       // 442368
  float* Hbuf  = Cst + 442368;       // 663552  (2*96*NC*16)
  float* yT    = Hbuf + 663552;      // 2654208   total ~42.0 MB
  float* Pbuf  = xxT;                // reuse: 663552 floats over xxT+xconv

  s1_inproj<<<2 * LSP, 192, 0, stream>>>(x, in_proj_w, xxT, z);
  s2_conv<<<2 * 96 * 9, 192, 0, stream>>>(xxT, conv_w, conv_b, xconv);
  s3_dirs<<<2 * 96 * P8 / 256, 256, 0, stream>>>(xconv, xs);
  s4_proj<<<2 * P8 / 64, 256, 0, stream>>>(xs, x_proj_w, dt_w, dt_b, delta, Bst, Cst);
  s5a_chunk<<<2 * NC, 128, 0, stream>>>(delta, xs, Bst, A_logs, Pbuf, Hbuf);
  s5a2_prefix<<<12, 256, 0, stream>>>(Pbuf, Hbuf);
  s5b_scan<<<2 * NC, 128, 0, stream>>>(delta, xs, Bst, Cst, Pbuf, A_logs, Ds, yT);
  s6_out<<<2 * 216, 128, 0, stream>>>(yT, z, ln_w, ln_b, out_proj_w, out);
}

// Round 4
// 164.545 us; speedup vs baseline: 1.2369x; 1.2369x over previous
//
#include <hip/hip_runtime.h>
#include <hip/hip_bf16.h>

// SS3D selective-scan block, MI355X (gfx950)
// B=2, D_INNER=96, D_MODEL=96, D_STATE=16, DT_RANK=6, L=12^3=1728, 8L=13824
//
//  S1: xz = x @ in_proj_w.T  -> xxT[b][c][l] (conv layout), z[b][l][c]
//  S2: depthwise conv3d 3x3x3 SAME + bias + silu -> xconv[b][c][l]
//  S3: 8 direction permutations -> xs[b][d][p]
//  S4: x_dbl = x_proj_w @ xs; delta = softplus(...); Bst/Cst[b][p][n]
//  S5: chunked scan. Parallelism = (b, chunk, d-half, 4-state-group):
//      864 blocks x 192 thr (48 d x 4 g), 4 states in regs per thread.
//      s5a: local (prodA, H), no cross-lane. prefix in-place. s5b: replay,
//      y = quad shfl-reduce over the 4 state-groups.
//  S6: mean over 8 dirs, LayerNorm, *silu(z), @ out_proj_w.T

#define LSP 1728
#define P8  13824
#define CS  64
#define NC  216
#define DH  48     // d-channels per scan block (96/2)

__device__ __forceinline__ float sigmoidf_(float v) { return 1.f / (1.f + __expf(-v)); }

// ---------- S1: input projection ----------
__global__ void s1_inproj(const float* __restrict__ x, const float* __restrict__ w,
                          float* __restrict__ xxT, float* __restrict__ z) {
  __shared__ float xr[96];
  int bl = blockIdx.x;            // b*1728 + l
  int b = bl / LSP, l = bl % LSP;
  int tid = threadIdx.x;          // 0..191 -> output channel c'
  if (tid < 96) xr[tid] = x[bl * 96 + tid];
  __syncthreads();
  float acc = 0.f;
  const float* wr = w + tid * 96;
#pragma unroll 8
  for (int c = 0; c < 96; c++) acc = fmaf(xr[c], wr[c], acc);
  if (tid < 96) xxT[(b * 96 + tid) * LSP + l] = acc;
  else          z[(b * LSP + l) * 96 + (tid - 96)] = acc;
}

// ---------- S2: depthwise conv3d + silu ----------
__global__ void s2_conv(const float* __restrict__ xxT, const float* __restrict__ cw,
                        const float* __restrict__ cb, float* __restrict__ xconv) {
  __shared__ float w[27];
  int bx = blockIdx.x;                 // b*(96*9) + c*9 + lb
  int b = bx / (96 * 9);
  int rem = bx % (96 * 9);
  int c = rem / 9, lb = rem % 9;
  int tid = threadIdx.x;               // 0..191
  if (tid < 27) w[tid] = cw[c * 27 + tid];
  __syncthreads();
  int l = lb * 192 + tid;
  int a = l / 144, r2 = l % 144, bb = r2 / 12, cc = r2 % 12;
  const float* xp = xxT + (b * 96 + c) * LSP;
  float acc = cb[c];
#pragma unroll
  for (int kd = -1; kd <= 1; kd++) {
    int ia = a + kd; if (ia < 0 || ia >= 12) continue;
#pragma unroll
    for (int kw = -1; kw <= 1; kw++) {
      int ib = bb + kw; if (ib < 0 || ib >= 12) continue;
#pragma unroll
      for (int kh = -1; kh <= 1; kh++) {
        int ic = cc + kh; if (ic < 0 || ic >= 12) continue;
        acc = fmaf(xp[ia * 144 + ib * 12 + ic], w[(kd + 1) * 9 + (kw + 1) * 3 + (kh + 1)], acc);
      }
    }
  }
  xconv[(b * 96 + c) * LSP + l] = acc * sigmoidf_(acc);
}

// ---------- S3: direction gather ----------
__global__ void s3_dirs(const float* __restrict__ xconv, float* __restrict__ xs) {
  int t = blockIdx.x * 256 + threadIdx.x;     // < 2*96*13824
  int bd = t / P8, p = t % P8;
  int k = p / LSP, l = p % LSP;
  int lp = (k & 1) ? (LSP - 1 - l) : l;
  int a = lp / 144, r = lp % 144, bb = r / 12, cc = r % 12;
  int s;
  switch (k >> 1) {
    case 0:  s = a * 144 + cc * 12 + bb; break;   // swap(W,H)
    case 1:  s = cc * 144 + bb * 12 + a; break;   // swap(D,H)
    case 2:  s = bb * 144 + a * 12 + cc; break;   // swap(D,W)
    default: s = lp; break;                        // identity
  }
  xs[t] = xconv[bd * LSP + s];
}

// ---------- S4: x_proj + dt projection + softplus (LDS-tiled) ----------
__global__ void s4_proj(const float* __restrict__ xs, const float* __restrict__ xpw,
                        const float* __restrict__ dtw, const float* __restrict__ dtb,
                        float* __restrict__ delta, float* __restrict__ Bst,
                        float* __restrict__ Cst) {
  __shared__ float xt[96][64];     // 24 KB   xs tile
  __shared__ float w[40 * 96];     // 15 KB   x_proj_w padded to 40 rows
  __shared__ float dwv[96 * 6];
  __shared__ float dbv[96];
  __shared__ float accS[6][64];    // dt-rank sums broadcast
  int tid = threadIdx.x;
  int blk = blockIdx.x;
  int b = blk / (P8 / 64);
  int p0 = (blk % (P8 / 64)) * 64;
  for (int i = tid; i < 40 * 96; i += 256) w[i] = (i < 38 * 96) ? xpw[i] : 0.f;
  for (int i = tid; i < 96 * 6; i += 256) dwv[i] = dtw[i];
  if (tid < 96) dbv[tid] = dtb[tid];
  int pl = tid & 63, cg = tid >> 6;   // lane-in-wave = p, wave = channel group
  const float* xsb = xs + (size_t)b * 96 * P8 + p0 + pl;
#pragma unroll
  for (int d0 = 0; d0 < 96; d0 += 4)
    xt[d0 + cg][pl] = xsb[(size_t)(d0 + cg) * P8];
  __syncthreads();

  int c0 = cg * 10;
  float acc[10];
#pragma unroll
  for (int j = 0; j < 10; j++) acc[j] = 0.f;
  for (int d = 0; d < 96; d++) {
    float xv = xt[d][pl];
#pragma unroll
    for (int j = 0; j < 10; j++) acc[j] = fmaf(w[(c0 + j) * 96 + d], xv, acc[j]);
  }
  if (cg == 0) {
#pragma unroll
    for (int j = 0; j < 6; j++) accS[j][pl] = acc[j];
  }
  size_t pi = (size_t)b * P8 + p0 + pl;
#pragma unroll
  for (int j = 0; j < 10; j++) {
    int c = c0 + j;
    if (c >= 6 && c < 22)       Bst[pi * 16 + (c - 6)]  = acc[j];
    else if (c >= 22 && c < 38) Cst[pi * 16 + (c - 22)] = acc[j];
  }
  __syncthreads();
  float a0 = accS[0][pl], a1 = accS[1][pl], a2 = accS[2][pl];
  float a3 = accS[3][pl], a4 = accS[4][pl], a5 = accS[5][pl];
  float* dout = delta + (size_t)b * 96 * P8 + p0 + pl;
#pragma unroll 4
  for (int dd = 0; dd < 24; dd++) {
    int d = cg * 24 + dd;
    const float* dwr = dwv + d * 6;
    float s = dbv[d];
    s = fmaf(dwr[0], a0, s); s = fmaf(dwr[1], a1, s); s = fmaf(dwr[2], a2, s);
    s = fmaf(dwr[3], a3, s); s = fmaf(dwr[4], a4, s); s = fmaf(dwr[5], a5, s);
    float sp = (s > 20.f) ? s : __logf(1.f + __expf(s));
    dout[(size_t)d * P8] = sp;
  }
}

// ---------- S5A: per-chunk scan, 4 states/thread, no cross-lane ----------
// grid = 2*NC*2 (b, chunk, d-half), 192 threads (48 d x 4 g)
__global__ void s5a_chunk(const float* __restrict__ delta, const float* __restrict__ xs,
                          const float* __restrict__ Bst, const float* __restrict__ A_logs,
                          float* __restrict__ P, float* __restrict__ H) {
  __shared__ float sdT[CS][DH + 1];
  __shared__ float sxT[CS][DH + 1];
  __shared__ float sB[CS][16];
  int bx = blockIdx.x;
  int b = bx / (NC * 2);
  int rem = bx % (NC * 2);
  int c = rem >> 1, hh = rem & 1;
  int tid = threadIdx.x;               // 192
  int p0 = c * CS;
  size_t rowbase = (size_t)(b * 96 + hh * DH) * P8 + p0;
#pragma unroll
  for (int k = 0; k < 4; k++) {
    int idx = tid + 192 * k;           // < 768 = 48 rows * 16 float4
    int dl = idx >> 4, i4 = idx & 15;
    float4 dv4 = *(const float4*)(delta + rowbase + (size_t)dl * P8 + i4 * 4);
    float4 xv4 = *(const float4*)(xs    + rowbase + (size_t)dl * P8 + i4 * 4);
    int i = i4 * 4;
    sdT[i][dl] = dv4.x; sdT[i+1][dl] = dv4.y; sdT[i+2][dl] = dv4.z; sdT[i+3][dl] = dv4.w;
    sxT[i][dl] = xv4.x; sxT[i+1][dl] = xv4.y; sxT[i+2][dl] = xv4.z; sxT[i+3][dl] = xv4.w;
  }
  {
    const float4* gB = (const float4*)(Bst + (size_t)(b * P8 + p0) * 16);
    float4* sB4 = (float4*)&sB[0][0];
    for (int i = tid; i < 256; i += 192) sB4[i] = gB[i];
  }
  __syncthreads();
  int dl = tid >> 2, g = tid & 3;
  int d = hh * DH + dl;
  float4 a4 = *(const float4*)(A_logs + d * 16 + g * 4);
  float Av[4] = { -__expf(a4.x) * 1.44269504f, -__expf(a4.y) * 1.44269504f,
                  -__expf(a4.z) * 1.44269504f, -__expf(a4.w) * 1.44269504f };
  float Pv[4] = {1.f, 1.f, 1.f, 1.f};
  float Hv[4] = {0.f, 0.f, 0.f, 0.f};
#pragma unroll 4
  for (int i = 0; i < CS; i++) {
    float dv = sdT[i][dl];
    float xv = sxT[i][dl];
    float dvx = dv * xv;
    float4 bq = *(const float4*)&sB[i][g * 4];
#pragma unroll
    for (int j = 0; j < 4; j++) {
      float bj = (j == 0) ? bq.x : (j == 1) ? bq.y : (j == 2) ? bq.z : bq.w;
      float dA = exp2f(dv * Av[j]);
      Pv[j] *= dA;
      Hv[j] = fmaf(dA, Hv[j], bj * dvx);
    }
  }
  size_t idx = ((size_t)(b * 96 + d) * NC + c) * 16 + g * 4;
  *(float4*)(P + idx) = make_float4(Pv[0], Pv[1], Pv[2], Pv[3]);
  *(float4*)(H + idx) = make_float4(Hv[0], Hv[1], Hv[2], Hv[3]);
}

// ---------- S5A2: chunk prefix, Hinit written IN-PLACE into P ----------
__global__ void s5a2_prefix(float* __restrict__ P, const float* __restrict__ H) {
  int t = blockIdx.x * 256 + threadIdx.x;   // < 2*96*16 = 3072
  int bd = t >> 4, n = t & 15;
  float* Pp = P + (size_t)bd * NC * 16 + n;
  const float* Hp = H + (size_t)bd * NC * 16 + n;
  float carry = 0.f;
#pragma unroll 4
  for (int c = 0; c < NC; c++) {
    float pv = Pp[(size_t)c * 16];
    float hv = Hp[(size_t)c * 16];
    Pp[(size_t)c * 16] = carry;          // init state for chunk c
    carry = fmaf(pv, carry, hv);
  }
}

// ---------- S5B: replay with init, emit y (quad shfl reduce) ----------
__global__ void s5b_scan(const float* __restrict__ delta, const float* __restrict__ xs,
                         const float* __restrict__ Bst, const float* __restrict__ Cst,
                         const float* __restrict__ Hinit, const float* __restrict__ A_logs,
                         const float* __restrict__ Ds, float* __restrict__ yT) {
  __shared__ float sdT[CS][DH + 1];
  __shared__ float sxT[CS][DH + 1];
  __shared__ float sB[CS][16];
  __shared__ float sC[CS][16];
  int bx = blockIdx.x;
  int b = bx / (NC * 2);
  int rem = bx % (NC * 2);
  int c = rem >> 1, hh = rem & 1;
  int tid = threadIdx.x;               // 192
  int p0 = c * CS;
  size_t rowbase = (size_t)(b * 96 + hh * DH) * P8 + p0;
#pragma unroll
  for (int k = 0; k < 4; k++) {
    int idx = tid + 192 * k;
    int dl = idx >> 4, i4 = idx & 15;
    float4 dv4 = *(const float4*)(delta + rowbase + (size_t)dl * P8 + i4 * 4);
    float4 xv4 = *(const float4*)(xs    + rowbase + (size_t)dl * P8 + i4 * 4);
    int i = i4 * 4;
    sdT[i][dl] = dv4.x; sdT[i+1][dl] = dv4.y; sdT[i+2][dl] = dv4.z; sdT[i+3][dl] = dv4.w;
    sxT[i][dl] = xv4.x; sxT[i+1][dl] = xv4.y; sxT[i+2][dl] = xv4.z; sxT[i+3][dl] = xv4.w;
  }
  {
    const float4* gB = (const float4*)(Bst + (size_t)(b * P8 + p0) * 16);
    const float4* gC = (const float4*)(Cst + (size_t)(b * P8 + p0) * 16);
    float4* sB4 = (float4*)&sB[0][0];
    float4* sC4 = (float4*)&sC[0][0];
    for (int i = tid; i < 256; i += 192) { sB4[i] = gB[i]; sC4[i] = gC[i]; }
  }
  __syncthreads();
  int dl = tid >> 2, g = tid & 3;
  int d = hh * DH + dl;
  float4 a4 = *(const float4*)(A_logs + d * 16 + g * 4);
  float Av[4] = { -__expf(a4.x) * 1.44269504f, -__expf(a4.y) * 1.44269504f,
                  -__expf(a4.z) * 1.44269504f, -__expf(a4.w) * 1.44269504f };
  float hv[4];
  size_t hidx = ((size_t)(b * 96 + d) * NC + c) * 16 + g * 4;
  float4 h4 = *(const float4*)(Hinit + hidx);
  hv[0] = h4.x; hv[1] = h4.y; hv[2] = h4.z; hv[3] = h4.w;
  float dsv = Ds[d];
  float* yp = yT + (size_t)(b * P8 + p0) * 96 + d;
#pragma unroll 4
  for (int i = 0; i < CS; i++) {
    float dv = sdT[i][dl];
    float xv = sxT[i][dl];
    float dvx = dv * xv;
    float4 bq = *(const float4*)&sB[i][g * 4];
    float4 cq = *(const float4*)&sC[i][g * 4];
    float val = 0.f;
#pragma unroll
    for (int j = 0; j < 4; j++) {
      float bj = (j == 0) ? bq.x : (j == 1) ? bq.y : (j == 2) ? bq.z : bq.w;
      float cj = (j == 0) ? cq.x : (j == 1) ? cq.y : (j == 2) ? cq.z : cq.w;
      float dA = exp2f(dv * Av[j]);
      hv[j] = fmaf(dA, hv[j], bj * dvx);
      val = fmaf(hv[j], cj, val);
    }
    val += __shfl_xor(val, 1, 4);
    val += __shfl_xor(val, 2, 4);
    if (g == 0) yp[(size_t)i * 96] = fmaf(xv, dsv, val);
  }
}

// ---------- S6: dir-mean + LayerNorm + gate + out_proj ----------
__global__ void s6_out(const float* __restrict__ yT, const float* __restrict__ z,
                       const float* __restrict__ lnw, const float* __restrict__ lnb,
                       const float* __restrict__ wout, float* __restrict__ out) {
  __shared__ float wl[96 * 97];   // padded stride 97 -> conflict-free
  __shared__ float g[96];
  __shared__ float r1[128], r2[128];
  int tid = threadIdx.x;          // 128
  for (int i = tid; i < 96 * 96; i += 128) {
    int cc = i / 96, dd = i % 96;
    wl[cc * 97 + dd] = wout[i];
  }
  int bx = blockIdx.x;            // b*216 + lb  (8 l's per block)
  int b = bx / 216, lb = bx % 216;
  __syncthreads();
  for (int j = 0; j < 8; j++) {
    int l = lb * 8 + j;
    float ym = 0.f, zv = 0.f;
    if (tid < 96) {
      const float* yp = yT + (size_t)(b * P8 + l) * 96 + tid;
#pragma unroll
      for (int k = 0; k < 8; k++) ym += yp[(size_t)k * LSP * 96];
      ym *= 0.125f;
      zv = z[(b * LSP + l) * 96 + tid];
    }
    r1[tid] = (tid < 96) ? ym : 0.f;
    r2[tid] = (tid < 96) ? ym * ym : 0.f;
    __syncthreads();
    for (int s = 64; s > 0; s >>= 1) {
      if (tid < s) { r1[tid] += r1[tid + s]; r2[tid] += r2[tid + s]; }
      __syncthreads();
    }
    float mu = r1[0] * (1.f / 96.f);
    float var = r2[0] * (1.f / 96.f) - mu * mu;
    float rstd = rsqrtf(var + 1e-5f);
    if (tid < 96) {
      float yn = (ym - mu) * rstd * lnw[tid] + lnb[tid];
      g[tid] = yn * (zv * sigmoidf_(zv));
    }
    __syncthreads();
    if (tid < 96) {
      float acc = 0.f;
#pragma unroll 8
      for (int dd = 0; dd < 96; dd++) acc = fmaf(g[dd], wl[tid * 97 + dd], acc);
      out[(b * LSP + l) * 96 + tid] = acc;
    }
    __syncthreads();
  }
}

extern "C" void kernel_launch(void* const* d_in, const int* in_sizes, int n_in,
                              void* d_out, int out_size, void* d_ws, size_t ws_size,
                              hipStream_t stream) {
  const float* x          = (const float*)d_in[0];
  const float* in_proj_w  = (const float*)d_in[1];
  const float* conv_w     = (const float*)d_in[2];
  const float* conv_b     = (const float*)d_in[3];
  const float* x_proj_w   = (const float*)d_in[4];
  const float* dt_w       = (const float*)d_in[5];
  const float* dt_b       = (const float*)d_in[6];
  const float* A_logs     = (const float*)d_in[7];
  const float* Ds         = (const float*)d_in[8];
  const float* ln_w       = (const float*)d_in[9];
  const float* ln_b       = (const float*)d_in[10];
  const float* out_proj_w = (const float*)d_in[11];
  float* out = (float*)d_out;

  float* ws    = (float*)d_ws;
  float* z     = ws;                 // 331776
  float* xxT   = z + 331776;         // 331776   (dead after s2; P overlays xxT+xconv)
  float* xconv = xxT + 331776;       // 331776   (dead after s3)
  float* xs    = xconv + 331776;     // 2654208
  float* delta = xs + 2654208;       // 2654208
  float* Bst   = delta + 2654208;    // 442368
  float* Cst   = Bst + 442368;       // 442368
  float* Hbuf  = Cst + 442368;       // 663552  (2*96*NC*16)
  float* yT    = Hbuf + 663552;      // 2654208   total ~42.0 MB
  float* Pbuf  = xxT;                // reuse: 663552 floats over xxT+xconv

  s1_inproj<<<2 * LSP, 192, 0, stream>>>(x, in_proj_w, xxT, z);
  s2_conv<<<2 * 96 * 9, 192, 0, stream>>>(xxT, conv_w, conv_b, xconv);
  s3_dirs<<<2 * 96 * P8 / 256, 256, 0, stream>>>(xconv, xs);
  s4_proj<<<2 * P8 / 64, 256, 0, stream>>>(xs, x_proj_w, dt_w, dt_b, delta, Bst, Cst);
  s5a_chunk<<<2 * NC * 2, 192, 0, stream>>>(delta, xs, Bst, A_logs, Pbuf, Hbuf);
  s5a2_prefix<<<12, 256, 0, stream>>>(Pbuf, Hbuf);
  s5b_scan<<<2 * NC * 2, 192, 0, stream>>>(delta, xs, Bst, Cst, Pbuf, A_logs, Ds, yT);
  s6_out<<<2 * 216, 128, 0, stream>>>(yT, z, ln_w, ln_b, out_proj_w, out);
}